// Round 7
// baseline (1166.684 us; speedup 1.0000x reference)
//
#include <hip/hip_runtime.h>
#include <hip/hip_cooperative_groups.h>

namespace cg = cooperative_groups;

// MetaTransformer collapse: per layer,
//   G[b]  = Zx[b,:2047]^T Zx[b,:2047]   (256x256)   gcol = Zx^T zlab
//   V     = G Pcat^T  (256 x 2048 stacked heads);  M^T = Vt3 Qcat2^T  (K=2048)
//   mcol  = (1/N) Qsum gcol
//   Z[b] += Zx[b] M[b]  (+ label-col GEMV with mcol)
// Single persistent cooperative kernel: all stages as grid-stride job loops
// separated by grid.sync(). XCD co-location via b = job&7. Fallback: round-6
// multi-kernel path if cooperative launch is unavailable.

#define NL   4
#define NH   8
#define DD   256
#define NCH  257
#define NTOK 2048
#define NVAL 2047
#define NB   8

typedef short  short8v __attribute__((ext_vector_type(8)));
typedef short  short4v __attribute__((ext_vector_type(4)));
typedef float  f32x4   __attribute__((ext_vector_type(4)));

__device__ __forceinline__ unsigned short f2b(float x) {
  union { float f; unsigned u; } v; v.f = x;
  unsigned u = v.u + 0x7fffu + ((v.u >> 16) & 1u);
  return (unsigned short)(u >> 16);
}
__device__ __forceinline__ float b2f(short s) {
  union { unsigned u; float f; } v; v.u = ((unsigned)(unsigned short)s) << 16;
  return v.f;
}

// ---- MFMA tile helper: one wave computes (NF*16) x (NG*16), K in [k0,k1).
template <int NF, int NG>
__device__ __forceinline__ void mm_tile_t(const short* A, const short* B, int lda, int ldb,
                                          int ar, int bc, int k0, int k1, int lane,
                                          f32x4 (&acc)[NF][NG]) {
  #pragma unroll 2
  for (int kk = k0; kk < k1; kk += 32) {
    const int kc = kk + ((lane >> 4) << 3);
    short8v av[NF], bv[NG];
    #pragma unroll
    for (int f = 0; f < NF; ++f)
      av[f] = *(const short8v*)(A + (size_t)(ar + f * 16 + (lane & 15)) * lda + kc);
    #pragma unroll
    for (int g = 0; g < NG; ++g)
      bv[g] = *(const short8v*)(B + (size_t)(bc + g * 16 + (lane & 15)) * ldb + kc);
    #pragma unroll
    for (int f = 0; f < NF; ++f)
      #pragma unroll
      for (int g = 0; g < NG; ++g)
        acc[f][g] = __builtin_amdgcn_mfma_f32_16x16x32_bf16(av[f], bv[g], acc[f][g], 0, 0, 0);
  }
}

// ===================== job bodies (shared by fused + fallback) =====================

__device__ __forceinline__ void job_pcast(int job, int tid, const float* ap, short* Pbf) {
  const f32x4* src = (const f32x4*)ap;
  int q0 = (job * 256 + tid) * 2;
  #pragma unroll
  for (int u = 0; u < 2; ++u) {
    int q = q0 + u, lj = q >> 14, rc4 = q & 16383;
    f32x4 v = src[(size_t)(lj * 2) * 16384 + rc4];
    short4v o;
    #pragma unroll
    for (int i = 0; i < 4; ++i) o[i] = (short)f2b(v[i]);
    ((short4v*)Pbf)[(size_t)lj * 16384 + rc4] = o;
  }
}

__device__ __forceinline__ void job_qcat(int job, int tid, const float* ap, short* Qcat2) {
  int l = job >> 8, k = job & 255;
  int j = tid >> 5, t0 = (tid & 31) * 8;
  const float* s = ap + (size_t)((l * 8 + j) * 2 + 1) * 65536 + (size_t)k * 256 + t0;
  f32x4 a = *(const f32x4*)s, bq = *(const f32x4*)(s + 4);
  short8v o;
  #pragma unroll
  for (int i = 0; i < 4; ++i) { o[i] = (short)f2b(a[i]); o[4 + i] = (short)f2b(bq[i]); }
  *(short8v*)(Qcat2 + (size_t)(l * 256 + k) * 2048 + j * 256 + t0) = o;
}

__device__ __forceinline__ void job_qsumt(int job, int tid, const float* ap, float* QsumT,
                                          float (*lds)[65]) {
  int l = job >> 4, xx = job & 15;
  int k0 = (xx >> 2) * 64, t0 = (xx & 3) * 64;
  int c = tid & 63, r = tid >> 6;
  __syncthreads();
  #pragma unroll
  for (int i = 0; i < 16; ++i) {
    int k = r + i * 4;
    float s = 0.f;
    #pragma unroll
    for (int j = 0; j < 8; ++j)
      s += ap[(size_t)((l * 8 + j) * 2 + 1) * 65536 + (size_t)(k0 + k) * 256 + (t0 + c)];
    lds[k][c] = s;
  }
  __syncthreads();
  #pragma unroll
  for (int i = 0; i < 16; ++i) {
    int tl = r + i * 4;
    QsumT[(size_t)l * 65536 + (size_t)(t0 + tl) * 256 + (k0 + c)] = lds[c][tl];
  }
}

__device__ __forceinline__ void job_zstage(int job, int tid, const float* Zin,
                                           short* Zxbf, short* Zxt, float* zlab,
                                           float (*lds)[65]) {
  int x = job & 3, y = (job >> 2) & 31, b = job >> 7;
  int k0 = x * 64, m0 = y * 64;
  int c = tid & 63, r = tid >> 6;
  __syncthreads();
  #pragma unroll
  for (int i = 0; i < 16; ++i) {
    int mrow = r + i * 4, m = m0 + mrow;
    float v = Zin[((size_t)b * NTOK + m) * NCH + k0 + c];
    lds[mrow][c] = v;
    Zxbf[((size_t)b * NTOK + m) * DD + k0 + c] = (short)f2b(v);
  }
  if (x == 0 && tid < 64) {
    int m = m0 + tid;
    zlab[b * NTOK + m] = (m == NVAL) ? 0.f : Zin[((size_t)b * NTOK + m) * NCH + DD];
  }
  __syncthreads();
  #pragma unroll
  for (int i = 0; i < 16; ++i) {
    int krow = r + i * 4;
    float v = lds[c][krow];
    if (m0 + c == NVAL) v = 0.f;
    Zxt[((size_t)b * DD + k0 + krow) * NTOK + m0 + c] = (short)f2b(v);
  }
}

__device__ __forceinline__ void job_gram(int job, int tid, const short* Zxt, float* Gacc) {
  const int lane = tid & 63, w = tid >> 6;
  const int b = job & 7, r = job >> 3, t = r & 15, seg = r >> 4;
  const int r0 = (t >> 2) * 64, c0 = (t & 3) * 64;
  const int ar = r0 + (w >> 1) * 32, bc = c0 + (w & 1) * 32;
  const short* A = Zxt + (size_t)b * DD * NTOK;
  f32x4 acc[2][2];
  #pragma unroll
  for (int f = 0; f < 2; ++f) for (int g = 0; g < 2; ++g) for (int i = 0; i < 4; ++i) acc[f][g][i] = 0.f;
  mm_tile_t<2, 2>(A, A, NTOK, NTOK, ar, bc, seg * 256, seg * 256 + 256, lane, acc);
  float* out = Gacc + ((size_t)seg * 128 + b * 16 + t) * 4096;
  #pragma unroll
  for (int f = 0; f < 2; ++f)
    #pragma unroll
    for (int g = 0; g < 2; ++g)
      #pragma unroll
      for (int i = 0; i < 4; ++i)
        out[((w >> 1) * 32 + f * 16 + ((lane >> 4) << 2) + i) * 64 +
            (w & 1) * 32 + g * 16 + (lane & 15)] = acc[f][g][i];
}

__device__ __forceinline__ void job_gcol(int job, int tid, const short* Zxbf,
                                         const float* zlab, float* gcolacc, float* ldsf) {
  const int b = job & 7, seg = job >> 3;
  __syncthreads();
  ldsf[tid] = zlab[b * NTOK + seg * 256 + tid];
  __syncthreads();
  const short* base = Zxbf + ((size_t)b * NTOK + seg * 256) * DD + tid;
  float s = 0.f;
  #pragma unroll 8
  for (int m = 0; m < 256; ++m) s += b2f(base[(size_t)m * DD]) * ldsf[m];
  gcolacc[(seg * 8 + b) * 256 + tid] = s;
}

__device__ __forceinline__ void job_gred(int job, int tid, const float* Gacc, short* Gbf) {
  const int i0 = (job * 256 + tid) * 4;
  f32x4 s = {0.f, 0.f, 0.f, 0.f};
  #pragma unroll
  for (int seg = 0; seg < 8; ++seg) {
    f32x4 v = *(const f32x4*)(Gacc + (size_t)seg * 524288 + i0);
    #pragma unroll
    for (int i = 0; i < 4; ++i) s[i] += v[i];
  }
  const int b = i0 >> 16, rem = i0 & 65535;
  const int t = rem >> 12, rr = (rem >> 6) & 63, cc = rem & 63;
  const int row = (t >> 2) * 64 + rr, col = (t & 3) * 64 + cc;
  short4v o;
  #pragma unroll
  for (int i = 0; i < 4; ++i) o[i] = (short)f2b(s[i]);
  *(short4v*)(Gbf + (size_t)b * 65536 + (size_t)row * 256 + col) = o;
}

__device__ __forceinline__ void job_gcolred(int b, int tid, const float* gcolacc, float* gcol) {
  float s = 0.f;
  #pragma unroll
  for (int seg = 0; seg < 8; ++seg) s += gcolacc[(seg * 8 + b) * 256 + tid];
  gcol[b * 256 + tid] = s;
}

__device__ __forceinline__ void job_pv(int job, int tid, const short* Gbf, const short* Pbf,
                                       short* Vt3, int layer) {
  const int lane = tid & 63, w = tid >> 6;
  const int b = job & 7, t = job >> 3;
  const int r0 = (t & 3) * 64, c0 = (t >> 2) * 128;
  const int ar = r0 + (w & 1) * 32, bc = c0 + (w >> 1) * 64;
  const short* A = Gbf + (size_t)b * 65536;
  const short* B = Pbf + (size_t)layer * 8 * 65536;
  f32x4 acc[2][4];
  #pragma unroll
  for (int f = 0; f < 2; ++f) for (int g = 0; g < 4; ++g) for (int i = 0; i < 4; ++i) acc[f][g][i] = 0.f;
  mm_tile_t<2, 4>(A, B, 256, 256, ar, bc, 0, 256, lane, acc);
  short* out = Vt3 + (size_t)b * 524288;
  #pragma unroll
  for (int f = 0; f < 2; ++f) {
    const int tt0 = ar + f * 16 + ((lane >> 4) << 2);
    #pragma unroll
    for (int g = 0; g < 4; ++g) {
      const int jc = bc + g * 16 + (lane & 15);
      const int j = jc >> 8, c = jc & 255;
      short4v p;
      #pragma unroll
      for (int i = 0; i < 4; ++i) p[i] = (short)f2b(acc[f][g][i]);
      *(short4v*)(out + (size_t)c * 2048 + j * 256 + tt0) = p;
    }
  }
}

__device__ __forceinline__ void job_mcol(int b, int tid, const float* QsumT,
                                         const float* gcol, float* mcol, int layer,
                                         float* ldsf) {
  __syncthreads();
  ldsf[tid] = gcol[b * 256 + tid];
  __syncthreads();
  float s = 0.f;
  for (int t = 0; t < 256; ++t) s += QsumT[(size_t)layer * 65536 + (size_t)t * 256 + tid] * ldsf[t];
  mcol[b * 256 + tid] = s * (1.0f / (float)NVAL);
}

__device__ __forceinline__ void job_qm(int job, int tid, const short* Vt3,
                                       const short* Qcat2, float* Macc, int layer) {
  const int lane = tid & 63, w = tid >> 6;
  const int b = job & 7, r = job >> 3, t = r & 15, seg = r >> 4;
  const int c0 = (t >> 2) * 64, k0 = (t & 3) * 64;
  const int ar = c0 + (w >> 1) * 32, bc = k0 + (w & 1) * 32;
  const short* A = Vt3 + (size_t)b * 524288;
  const short* B = Qcat2 + (size_t)layer * 524288;
  f32x4 acc[2][2];
  #pragma unroll
  for (int f = 0; f < 2; ++f) for (int g = 0; g < 2; ++g) for (int i = 0; i < 4; ++i) acc[f][g][i] = 0.f;
  mm_tile_t<2, 2>(A, B, 2048, 2048, ar, bc, seg * 256, seg * 256 + 256, lane, acc);
  float* out = Macc + ((size_t)seg * 128 + b * 16 + t) * 4096;
  #pragma unroll
  for (int f = 0; f < 2; ++f)
    #pragma unroll
    for (int g = 0; g < 2; ++g)
      #pragma unroll
      for (int i = 0; i < 4; ++i)
        out[((w >> 1) * 32 + f * 16 + ((lane >> 4) << 2) + i) * 64 +
            (w & 1) * 32 + g * 16 + (lane & 15)] = acc[f][g][i];
}

__device__ __forceinline__ void job_mred(int job, int tid, const float* Macc, short* Mt) {
  const int i0 = (job * 256 + tid) * 4;
  f32x4 s = {0.f, 0.f, 0.f, 0.f};
  #pragma unroll
  for (int seg = 0; seg < 8; ++seg) {
    f32x4 v = *(const f32x4*)(Macc + (size_t)seg * 524288 + i0);
    #pragma unroll
    for (int i = 0; i < 4; ++i) s[i] += v[i];
  }
  const float invN = 1.0f / (float)NVAL;
  const int b = i0 >> 16, rem = i0 & 65535;
  const int t = rem >> 12, rr = (rem >> 6) & 63, cc = rem & 63;
  const int row = (t >> 2) * 64 + rr, col = (t & 3) * 64 + cc;
  short4v o;
  #pragma unroll
  for (int i = 0; i < 4; ++i) o[i] = (short)f2b(s[i] * invN);
  *(short4v*)(Mt + (size_t)b * 65536 + (size_t)row * 256 + col) = o;
}

__device__ __forceinline__ void job_apply(int job, int tid, const float* Zsrc, float* Z,
                                          const short* Zxin, const short* Mt,
                                          const float* mcol, short* Zxout,
                                          short* Zxt_out, float* zlab_out, int wnext,
                                          short (*ldsT)[66]) {
  const int lane = tid & 63, w = tid >> 6;
  const int b = job & 7, t = job >> 3;
  const int n0 = (t >> 1) * 64, c0 = (t & 1) * 128;
  const int bc = c0 + w * 32;
  const short* A = Zxin + (size_t)b * NTOK * DD;
  const short* B = Mt + (size_t)b * 65536;
  const bool gemv = (c0 == 0 && w == 0);
  __syncthreads();
  f32x4 acc[4][2];
  #pragma unroll
  for (int f = 0; f < 4; ++f) for (int g = 0; g < 2; ++g) for (int i = 0; i < 4; ++i) acc[f][g][i] = 0.f;
  float s[4] = {0.f, 0.f, 0.f, 0.f};
  #pragma unroll 2
  for (int kk = 0; kk < 256; kk += 32) {
    const int kc = kk + ((lane >> 4) << 3);
    short8v av[4], bv[2];
    #pragma unroll
    for (int f = 0; f < 4; ++f)
      av[f] = *(const short8v*)(A + (size_t)(n0 + f * 16 + (lane & 15)) * DD + kc);
    #pragma unroll
    for (int g = 0; g < 2; ++g)
      bv[g] = *(const short8v*)(B + (size_t)(bc + g * 16 + (lane & 15)) * 256 + kc);
    if (gemv) {
      const float* mp = mcol + b * 256 + kc;
      f32x4 m0 = *(const f32x4*)mp, m1 = *(const f32x4*)(mp + 4);
      #pragma unroll
      for (int f = 0; f < 4; ++f) {
        #pragma unroll
        for (int q = 0; q < 4; ++q) {
          s[f] += b2f(av[f][q]) * m0[q];
          s[f] += b2f(av[f][4 + q]) * m1[q];
        }
      }
    }
    #pragma unroll
    for (int f = 0; f < 4; ++f)
      #pragma unroll
      for (int g = 0; g < 2; ++g)
        acc[f][g] = __builtin_amdgcn_mfma_f32_16x16x32_bf16(av[f], bv[g], acc[f][g], 0, 0, 0);
  }
  #pragma unroll
  for (int f = 0; f < 4; ++f) {
    const int nr = n0 + f * 16 + ((lane >> 4) << 2);
    #pragma unroll
    for (int g = 0; g < 2; ++g) {
      const int c = bc + g * 16 + (lane & 15);
      #pragma unroll
      for (int i = 0; i < 4; ++i) {
        size_t idx = ((size_t)b * NTOK + nr + i) * NCH + c;
        float nv = Zsrc[idx] + acc[f][g][i];
        Z[idx] = nv;
        unsigned short bvv = f2b(nv);
        if (wnext) {
          Zxout[((size_t)b * NTOK + nr + i) * DD + c] = (short)bvv;
          ldsT[c - c0][nr - n0 + i] = (nr + i == NVAL) ? (short)0 : (short)bvv;
        }
      }
    }
  }
  if (gemv) {
    #pragma unroll
    for (int f = 0; f < 4; ++f) {
      float tt = s[f];
      tt += __shfl_xor(tt, 16);
      tt += __shfl_xor(tt, 32);
      if ((lane >> 4) == 0) {
        int n = n0 + f * 16 + (lane & 15);
        size_t idx = ((size_t)b * NTOK + n) * NCH + DD;
        float nv = Zsrc[idx] + tt;
        Z[idx] = nv;
        if (wnext) zlab_out[b * NTOK + n] = (n == NVAL) ? 0.f : nv;
      }
    }
  }
  if (wnext) {
    __syncthreads();
    const int cr = tid & 127, half = (tid >> 7) * 32;
    #pragma unroll
    for (int u = 0; u < 4; ++u) {
      short8v v = *(const short8v*)&ldsT[cr][half + u * 8];
      *(short8v*)(Zxt_out + ((size_t)b * DD + c0 + cr) * NTOK + n0 + half + u * 8) = v;
    }
  }
}

// ===================== fused persistent cooperative kernel =====================

__global__ __launch_bounds__(256) void k_fused(
    const float* __restrict__ Zin, const float* __restrict__ ap, float* __restrict__ Z,
    short* __restrict__ Zx0, short* __restrict__ Zx1, short* __restrict__ Zxt,
    float* __restrict__ Acc, short* __restrict__ Gbf, short* __restrict__ Vt3,
    short* __restrict__ Mt, short* __restrict__ Pbf, short* __restrict__ Qcat2,
    float* __restrict__ QsumT, float* __restrict__ gcolacc, float* __restrict__ gcol,
    float* __restrict__ mcol, float* __restrict__ zlab) {
  cg::grid_group grid = cg::this_grid();
  __shared__ __attribute__((aligned(16))) char smem[17408];
  float (*ldsA)[65] = (float(*)[65])smem;
  short (*ldsT)[66] = (short(*)[66])smem;
  float* ldsf = (float*)smem;
  const int tid = threadIdx.x;
  const int nwg = gridDim.x;

  // ---- S0: param prep + Z staging
  for (int job = blockIdx.x; job < 1024; job += nwg) job_pcast(job, tid, ap, Pbf);
  for (int job = blockIdx.x; job < 1024; job += nwg) job_qcat(job, tid, ap, Qcat2);
  for (int job = blockIdx.x; job < 64; job += nwg) job_qsumt(job, tid, ap, QsumT, ldsA);
  for (int job = blockIdx.x; job < 1024; job += nwg) job_zstage(job, tid, Zin, Zx0, Zxt, zlab, ldsA);
  grid.sync();

  for (int layer = 0; layer < NL; ++layer) {
    short* Zxcur = (layer & 1) ? Zx1 : Zx0;
    short* Zxnxt = (layer & 1) ? Zx0 : Zx1;
    const float* Zsrc = (layer == 0) ? Zin : Z;
    const int wnext = (layer < NL - 1) ? 1 : 0;

    for (int job = blockIdx.x; job < 1024; job += nwg) job_gram(job, tid, Zxt, Acc);
    for (int job = blockIdx.x; job < 64; job += nwg) job_gcol(job, tid, Zxcur, zlab, gcolacc, ldsf);
    grid.sync();

    for (int job = blockIdx.x; job < 512; job += nwg) job_gred(job, tid, Acc, Gbf);
    for (int job = blockIdx.x; job < 8; job += nwg) job_gcolred(job, tid, gcolacc, gcol);
    grid.sync();

    for (int job = blockIdx.x; job < 512; job += nwg) job_pv(job, tid, Gbf, Pbf, Vt3, layer);
    for (int job = blockIdx.x; job < 8; job += nwg) job_mcol(job, tid, QsumT, gcol, mcol, layer, ldsf);
    grid.sync();

    for (int job = blockIdx.x; job < 1024; job += nwg) job_qm(job, tid, Vt3, Qcat2, Acc, layer);
    grid.sync();

    for (int job = blockIdx.x; job < 512; job += nwg) job_mred(job, tid, Acc, Mt);
    grid.sync();

    for (int job = blockIdx.x; job < 512; job += nwg)
      job_apply(job, tid, Zsrc, Z, Zxcur, Mt, mcol, Zxnxt, Zxt, zlab, wnext, ldsT);
    if (layer < NL - 1) grid.sync();
  }
}

// ===================== fallback multi-kernel path (round-6) =====================

__global__ __launch_bounds__(256) void fb_prep(const float* __restrict__ ap,
                                               short* __restrict__ Pbf, short* __restrict__ Qcat2,
                                               float* __restrict__ QsumT) {
  __shared__ float lds[64][65];
  const int bx = blockIdx.x, tid = threadIdx.x;
  if (bx < 1024) { job_pcast(bx, tid, ap, Pbf); return; }
  if (bx < 2048) { job_qcat(bx - 1024, tid, ap, Qcat2); return; }
  job_qsumt(bx - 2048, tid, ap, QsumT, lds);
}
__global__ __launch_bounds__(256) void fb_zstage(const float* __restrict__ Zin,
                                                 short* __restrict__ Zxbf, short* __restrict__ Zxt,
                                                 float* __restrict__ zlab) {
  __shared__ float lds[64][65];
  job_zstage(blockIdx.x, threadIdx.x, Zin, Zxbf, Zxt, zlab, lds);
}
__global__ __launch_bounds__(256) void fb_gram(const short* __restrict__ Zxt,
                                               const short* __restrict__ Zxbf,
                                               const float* __restrict__ zlab,
                                               float* __restrict__ Gacc,
                                               float* __restrict__ gcolacc) {
  __shared__ float ldsf[256];
  const int x = blockIdx.x;
  if (x >= 1024) { job_gcol(x - 1024, threadIdx.x, Zxbf, zlab, gcolacc, ldsf); return; }
  job_gram(x, threadIdx.x, Zxt, Gacc);
}
__global__ __launch_bounds__(256) void fb_gred(const float* __restrict__ Gacc,
                                               const float* __restrict__ gcolacc,
                                               short* __restrict__ Gbf, float* __restrict__ gcol) {
  const int x = blockIdx.x;
  if (x >= 512) { job_gcolred(x - 512, threadIdx.x, gcolacc, gcol); return; }
  job_gred(x, threadIdx.x, Gacc, Gbf);
}
__global__ __launch_bounds__(256) void fb_pv(const short* __restrict__ Gbf, const short* __restrict__ Pbf,
                                             const float* __restrict__ QsumT, const float* __restrict__ gcol,
                                             short* __restrict__ Vt3, float* __restrict__ mcol, int layer) {
  __shared__ float ldsf[256];
  const int x = blockIdx.x;
  if (x >= 512) { job_mcol(x - 512, threadIdx.x, QsumT, gcol, mcol, layer, ldsf); return; }
  job_pv(x, threadIdx.x, Gbf, Pbf, Vt3, layer);
}
__global__ __launch_bounds__(256) void fb_qm(const short* __restrict__ Vt3, const short* __restrict__ Qcat2,
                                             float* __restrict__ Macc, int layer) {
  job_qm(blockIdx.x, threadIdx.x, Vt3, Qcat2, Macc, layer);
}
__global__ __launch_bounds__(256) void fb_mred(const float* __restrict__ Macc, short* __restrict__ Mt) {
  job_mred(blockIdx.x, threadIdx.x, Macc, Mt);
}
__global__ __launch_bounds__(256) void fb_apply(const float* __restrict__ Zsrc, float* __restrict__ Z,
                                                const short* __restrict__ Zxin, const short* __restrict__ Mt,
                                                const float* __restrict__ mcol,
                                                short* __restrict__ Zxout, short* __restrict__ Zxt_out,
                                                float* __restrict__ zlab_out, int wnext) {
  __shared__ short ldsT[128][66];
  job_apply(blockIdx.x, threadIdx.x, Zsrc, Z, Zxin, Mt, mcol, Zxout, Zxt_out, zlab_out, wnext, ldsT);
}

// =====================================================================================
extern "C" void kernel_launch(void* const* d_in, const int* in_sizes, int n_in,
                              void* d_out, int out_size, void* d_ws, size_t ws_size,
                              hipStream_t stream) {
  const float* Zin      = (const float*)d_in[0];
  const float* allparam = (const float*)d_in[1];
  float* Z = (float*)d_out;

  // ws layout (bytes)
  const size_t o_zx0  = 0;                         // bf16 [8][2048][256]   8,388,608 (ping)
  const size_t o_zx1  = o_zx0  + 8388608;          // bf16                  8,388,608 (pong)
  const size_t o_zxt  = o_zx1  + 8388608;          // bf16 [8][256][2048]   8,388,608
  const size_t o_acc  = o_zxt  + 8388608;          // f32  [8][128][4096]   16,777,216 (Gacc/Macc alias)
  const size_t o_gbf  = o_acc  + 16777216;         // bf16 [8][256][256]    1,048,576
  const size_t o_vt   = o_gbf  + 1048576;          // bf16 [8][256][2048]   8,388,608 (Vt3)
  const size_t o_mt   = o_vt   + 8388608;          // bf16 [8][256][256]    1,048,576
  const size_t o_pbf  = o_mt   + 1048576;          // bf16 [4][8][256][256] 4,194,304
  const size_t o_qc2  = o_pbf  + 4194304;          // bf16 [4][256][2048]   4,194,304 (Qcat2)
  const size_t o_qsum = o_qc2  + 4194304;          // f32  [4][256][256]    1,048,576
  const size_t o_gca  = o_qsum + 1048576;          // f32  [8][8][256]      65,536 (gcolacc)
  const size_t o_gcol = o_gca  + 65536;            // f32  [8][256]         8,192
  const size_t o_mcol = o_gcol + 8192;             // f32  [8][256]         8,192
  const size_t o_zlab = o_mcol + 8192;             // f32  [8][2048]        65,536
  const size_t NEED   = o_zlab + 65536;
  if (ws_size < NEED) return;                      // harness provides 256 MB; never hit

  char* wsb = (char*)d_ws;
  short* Zx0p    = (short*)(wsb + o_zx0);
  short* Zx1p    = (short*)(wsb + o_zx1);
  short* Zxtp    = (short*)(wsb + o_zxt);
  float* Accp    = (float*)(wsb + o_acc);
  short* Gbfp    = (short*)(wsb + o_gbf);
  short* Vt3p    = (short*)(wsb + o_vt);
  short* Mtp     = (short*)(wsb + o_mt);
  short* Pbfp    = (short*)(wsb + o_pbf);
  short* Qcat2p  = (short*)(wsb + o_qc2);
  float* QsumTp  = (float*)(wsb + o_qsum);
  float* gcolap  = (float*)(wsb + o_gca);
  float* gcolp   = (float*)(wsb + o_gcol);
  float* mcolp   = (float*)(wsb + o_mcol);
  float* zlabp   = (float*)(wsb + o_zlab);

  // ---- try single persistent cooperative kernel ----
  int nb = 0;
  hipError_t qe = hipOccupancyMaxActiveBlocksPerMultiprocessor(&nb, (const void*)k_fused, 256, 0);
  int grid = (qe == hipSuccess && nb > 0) ? nb * 256 : 512;   // 256 CUs on MI355X
  if (grid > 1024) grid = 1024;
  void* args[] = {
    (void*)&Zin, (void*)&allparam, (void*)&Z,
    (void*)&Zx0p, (void*)&Zx1p, (void*)&Zxtp, (void*)&Accp, (void*)&Gbfp,
    (void*)&Vt3p, (void*)&Mtp, (void*)&Pbfp, (void*)&Qcat2p, (void*)&QsumTp,
    (void*)&gcolap, (void*)&gcolp, (void*)&mcolp, (void*)&zlabp
  };
  hipError_t le = hipLaunchCooperativeKernel((void*)k_fused, dim3(grid), dim3(256), args, 0, stream);
  if (le == hipSuccess) return;

  // ---- fallback: round-6 multi-kernel path ----
  fb_prep<<<dim3(2112), dim3(256), 0, stream>>>(allparam, Pbfp, Qcat2p, QsumTp);
  fb_zstage<<<dim3(1024), dim3(256), 0, stream>>>(Zin, Zx0p, Zxtp, zlabp);
  for (int layer = 0; layer < NL; ++layer) {
    short* Zxcur = (layer & 1) ? Zx1p : Zx0p;
    short* Zxnxt = (layer & 1) ? Zx0p : Zx1p;
    const float* Zsrc = (layer == 0) ? Zin : Z;
    const int wnext = (layer < NL - 1) ? 1 : 0;
    fb_gram<<<dim3(1088), dim3(256), 0, stream>>>(Zxtp, Zxcur, zlabp, Accp, gcolap);
    fb_gred<<<dim3(520), dim3(256), 0, stream>>>(Accp, gcolap, Gbfp, gcolp);
    fb_pv<<<dim3(520), dim3(256), 0, stream>>>(Gbfp, Pbfp, QsumTp, gcolp, Vt3p, mcolp, layer);
    fb_qm<<<dim3(1024), dim3(256), 0, stream>>>(Vt3p, Qcat2p, Accp, layer);
    fb_mred<<<dim3(512), dim3(256), 0, stream>>>(Accp, Mtp);
    fb_apply<<<dim3(512), dim3(256), 0, stream>>>(Zsrc, Z, Zxcur, Mtp, mcolp,
                                                  Zxnxt, Zxtp, zlabp, wnext);
  }
}

// Round 8
// 400.340 us; speedup vs baseline: 2.9142x; 2.9142x over previous
//
#include <hip/hip_runtime.h>

// MetaTransformer collapse: per layer,
//   G[b]  = Zx[b,:2047]^T Zx[b,:2047]   (256x256)   gcol = Zx^T zlab
//   V     = G Pcat^T  (256 x 2048 stacked heads);  M^T = Vt3 Qcat2^T  (K=2048)
//   mcol  = (1/N) Qsum gcol
//   Z[b] += Zx[b] M[b]  (+ label-col GEMV with mcol)
// 64x64-per-wave MFMA tiles (16 MFMA / 8 loads per K-step), split-K across wgs
// with fp32 full-layout partials + linear reduce kernels. b = x&7 XCD
// co-location. 25 dispatches, every grid >= 256 wgs. No cooperative launch.

#define NL   4
#define NH   8
#define DD   256
#define NCH  257
#define NTOK 2048
#define NVAL 2047
#define NB   8

typedef short  short8v __attribute__((ext_vector_type(8)));
typedef short  short4v __attribute__((ext_vector_type(4)));
typedef float  f32x4   __attribute__((ext_vector_type(4)));

__device__ __forceinline__ unsigned short f2b(float x) {
  union { float f; unsigned u; } v; v.f = x;
  unsigned u = v.u + 0x7fffu + ((v.u >> 16) & 1u);
  return (unsigned short)(u >> 16);
}
__device__ __forceinline__ float b2f(short s) {
  union { unsigned u; float f; } v; v.u = ((unsigned)(unsigned short)s) << 16;
  return v.f;
}

// ---- MFMA tile: one wave computes 64x64 (4x4 fragments), K in [k0,k1).
__device__ __forceinline__ void mm64(const short* A, const short* B, int lda, int ldb,
                                     int ar, int bc, int k0, int k1, int lane,
                                     f32x4 (&acc)[4][4]) {
  #pragma unroll 2
  for (int kk = k0; kk < k1; kk += 32) {
    const int kc = kk + ((lane >> 4) << 3);
    short8v av[4], bv[4];
    #pragma unroll
    for (int f = 0; f < 4; ++f)
      av[f] = *(const short8v*)(A + (size_t)(ar + f * 16 + (lane & 15)) * lda + kc);
    #pragma unroll
    for (int g = 0; g < 4; ++g)
      bv[g] = *(const short8v*)(B + (size_t)(bc + g * 16 + (lane & 15)) * ldb + kc);
    #pragma unroll
    for (int f = 0; f < 4; ++f)
      #pragma unroll
      for (int g = 0; g < 4; ++g)
        acc[f][g] = __builtin_amdgcn_mfma_f32_16x16x32_bf16(av[f], bv[g], acc[f][g], 0, 0, 0);
  }
}

// ---- k_init: flat grid 3136.
//   [0,1024)     P cast -> Pbf
//   [1024,2048)  Q permute-cast -> Qcat2[l][k][j*256+t]
//   [2048,2112)  QsumT[l][t][k] = sum_j Q_j[k][t]
//   [2112,3136)  Zin -> Zxbf (natural bf16), Zxt (transposed, m=2047 zeroed), zlab
__global__ __launch_bounds__(256) void k_init(const float* __restrict__ Zin,
                                              const float* __restrict__ ap,
                                              short* __restrict__ Pbf, short* __restrict__ Qcat2,
                                              float* __restrict__ QsumT,
                                              short* __restrict__ Zxbf, short* __restrict__ Zxt,
                                              float* __restrict__ zlab) {
  __shared__ float lds[64][65];
  const int bx = blockIdx.x, tid = threadIdx.x;
  if (bx < 1024) {
    const f32x4* src = (const f32x4*)ap;
    int q0 = (bx * 256 + tid) * 2;
    #pragma unroll
    for (int u = 0; u < 2; ++u) {
      int q = q0 + u, lj = q >> 14, rc4 = q & 16383;
      f32x4 v = src[(size_t)(lj * 2) * 16384 + rc4];
      short4v o;
      #pragma unroll
      for (int i = 0; i < 4; ++i) o[i] = (short)f2b(v[i]);
      ((short4v*)Pbf)[(size_t)lj * 16384 + rc4] = o;
    }
    return;
  }
  if (bx < 2048) {
    int idx = bx - 1024;
    int l = idx >> 8, k = idx & 255;
    int j = tid >> 5, t0 = (tid & 31) * 8;
    const float* s = ap + (size_t)((l * 8 + j) * 2 + 1) * 65536 + (size_t)k * 256 + t0;
    f32x4 a = *(const f32x4*)s, bq = *(const f32x4*)(s + 4);
    short8v o;
    #pragma unroll
    for (int i = 0; i < 4; ++i) { o[i] = (short)f2b(a[i]); o[4 + i] = (short)f2b(bq[i]); }
    *(short8v*)(Qcat2 + (size_t)(l * 256 + k) * 2048 + j * 256 + t0) = o;
    return;
  }
  if (bx < 2112) {
    int qb = bx - 2048;
    int l = qb >> 4, xx = qb & 15;
    int k0 = (xx >> 2) * 64, t0 = (xx & 3) * 64;
    int c = tid & 63, r = tid >> 6;
    #pragma unroll
    for (int i = 0; i < 16; ++i) {
      int k = r + i * 4;
      float s = 0.f;
      #pragma unroll
      for (int j = 0; j < 8; ++j)
        s += ap[(size_t)((l * 8 + j) * 2 + 1) * 65536 + (size_t)(k0 + k) * 256 + (t0 + c)];
      lds[k][c] = s;
    }
    __syncthreads();
    #pragma unroll
    for (int i = 0; i < 16; ++i) {
      int tl = r + i * 4;
      QsumT[(size_t)l * 65536 + (size_t)(t0 + tl) * 256 + (k0 + c)] = lds[c][tl];
    }
    return;
  }
  int tb = bx - 2112;
  int x = tb & 3, y = (tb >> 2) & 31, b = tb >> 7;
  int k0 = x * 64, m0 = y * 64;
  int c = tid & 63, r = tid >> 6;
  #pragma unroll
  for (int i = 0; i < 16; ++i) {
    int mrow = r + i * 4, m = m0 + mrow;
    float v = Zin[((size_t)b * NTOK + m) * NCH + k0 + c];
    lds[mrow][c] = v;
    Zxbf[((size_t)b * NTOK + m) * DD + k0 + c] = (short)f2b(v);
  }
  if (x == 0 && tid < 64) {
    int m = m0 + tid;
    zlab[b * NTOK + m] = (m == NVAL) ? 0.f : Zin[((size_t)b * NTOK + m) * NCH + DD];
  }
  __syncthreads();
  #pragma unroll
  for (int i = 0; i < 16; ++i) {
    int krow = r + i * 4;
    float v = lds[c][krow];
    if (m0 + c == NVAL) v = 0.f;
    Zxt[((size_t)b * DD + k0 + krow) * NTOK + m0 + c] = (short)f2b(v);
  }
}

// ---- k_gram: grid 576. x<512: b=x&7, tile=(x>>3)&3 (128x128 quadrant),
//      seg=x>>5 (K=128 window) -> Gacc[(seg*8+b)][row*256+col] fp32.
//      x>=512: gcol partials over 256-m segment via Zxbf.
__global__ __launch_bounds__(256) void k_gram(const short* __restrict__ Zxt,
                                              const short* __restrict__ Zxbf,
                                              const float* __restrict__ zlab,
                                              float* __restrict__ Gacc,
                                              float* __restrict__ gcolacc) {
  __shared__ float zl[256];
  const int x = blockIdx.x, tid = threadIdx.x;
  if (x >= 512) {
    const int idx = x - 512, b = idx & 7, seg = idx >> 3;
    zl[tid] = zlab[b * NTOK + seg * 256 + tid];
    __syncthreads();
    const short* base = Zxbf + ((size_t)b * NTOK + seg * 256) * DD + tid;
    float s = 0.f;
    #pragma unroll 8
    for (int m = 0; m < 256; ++m) s += b2f(base[(size_t)m * DD]) * zl[m];
    gcolacc[(seg * 8 + b) * 256 + tid] = s;
    return;
  }
  const int lane = tid & 63, wid = tid >> 6;
  const int b = x & 7, t = (x >> 3) & 3, seg = x >> 5;
  const int r0 = (t >> 1) * 128, c0 = (t & 1) * 128;
  const int ar = r0 + (wid >> 1) * 64, bc = c0 + (wid & 1) * 64;
  const short* A = Zxt + (size_t)b * DD * NTOK;
  f32x4 acc[4][4];
  #pragma unroll
  for (int f = 0; f < 4; ++f) for (int g = 0; g < 4; ++g) for (int i = 0; i < 4; ++i) acc[f][g][i] = 0.f;
  mm64(A, A, NTOK, NTOK, ar, bc, seg * 128, seg * 128 + 128, lane, acc);
  float* out = Gacc + (size_t)(seg * 8 + b) * 65536;
  #pragma unroll
  for (int f = 0; f < 4; ++f)
    #pragma unroll
    for (int g = 0; g < 4; ++g)
      #pragma unroll
      for (int i = 0; i < 4; ++i)
        out[(size_t)(ar + f * 16 + ((lane >> 4) << 2) + i) * 256 + bc + g * 16 + (lane & 15)] = acc[f][g][i];
}

// ---- k_gred: grid 520. x<512: linear 16-seg reduce -> Gbf. x>=512: gcol 8-seg reduce.
__global__ __launch_bounds__(256) void k_gred(const float* __restrict__ Gacc,
                                              const float* __restrict__ gcolacc,
                                              short* __restrict__ Gbf, float* __restrict__ gcol) {
  const int x = blockIdx.x, tid = threadIdx.x;
  if (x >= 512) {
    const int b = x - 512;
    float s = 0.f;
    #pragma unroll
    for (int seg = 0; seg < 8; ++seg) s += gcolacc[(seg * 8 + b) * 256 + tid];
    gcol[b * 256 + tid] = s;
    return;
  }
  const int i0 = (x * 256 + tid) * 4;
  const int b = i0 >> 16, el = i0 & 65535;
  f32x4 s = {0.f, 0.f, 0.f, 0.f};
  #pragma unroll
  for (int seg = 0; seg < 16; ++seg) {
    f32x4 v = *(const f32x4*)(Gacc + (size_t)(seg * 8 + b) * 65536 + el);
    #pragma unroll
    for (int i = 0; i < 4; ++i) s[i] += v[i];
  }
  short4v o;
  #pragma unroll
  for (int i = 0; i < 4; ++i) o[i] = (short)f2b(s[i]);
  *(short4v*)(Gbf + (size_t)b * 65536 + el) = o;
}

// ---- k_pv: grid 264. x<256: b=x&7, t=x>>3 (0..31): 128t x 128jc tile of V = G Pcat^T;
//      write Vt3[b][c][j*256+t]. x>=256: mcol = invN * QsumT gcol.
__global__ __launch_bounds__(256) void k_pv(const short* __restrict__ Gbf, const short* __restrict__ Pbf,
                                            const float* __restrict__ QsumT, const float* __restrict__ gcol,
                                            short* __restrict__ Vt3, float* __restrict__ mcol, int layer) {
  __shared__ float gs[256];
  const int x = blockIdx.x, tid = threadIdx.x;
  if (x >= 256) {
    const int b = x - 256;
    gs[tid] = gcol[b * 256 + tid];
    __syncthreads();
    float s = 0.f;
    for (int t = 0; t < 256; ++t) s += QsumT[(size_t)layer * 65536 + (size_t)t * 256 + tid] * gs[t];
    mcol[b * 256 + tid] = s * (1.0f / (float)NVAL);
    return;
  }
  const int lane = tid & 63, wid = tid >> 6;
  const int b = x & 7, t = x >> 3;
  const int r0 = (t & 1) * 128, c0 = (t >> 1) * 128;   // r0: t-dim (2 tiles), c0: jc (16 tiles)
  const int ar = r0 + (wid >> 1) * 64, bc = c0 + (wid & 1) * 64;
  const short* A = Gbf + (size_t)b * 65536;
  const short* B = Pbf + (size_t)layer * 8 * 65536;
  f32x4 acc[4][4];
  #pragma unroll
  for (int f = 0; f < 4; ++f) for (int g = 0; g < 4; ++g) for (int i = 0; i < 4; ++i) acc[f][g][i] = 0.f;
  mm64(A, B, 256, 256, ar, bc, 0, 256, lane, acc);
  short* out = Vt3 + (size_t)b * 524288;
  #pragma unroll
  for (int f = 0; f < 4; ++f) {
    const int tt0 = ar + f * 16 + ((lane >> 4) << 2);
    #pragma unroll
    for (int g = 0; g < 4; ++g) {
      const int jc = bc + g * 16 + (lane & 15);
      const int j = jc >> 8, c = jc & 255;
      short4v p;
      #pragma unroll
      for (int i = 0; i < 4; ++i) p[i] = (short)f2b(acc[f][g][i]);
      *(short4v*)(out + (size_t)c * 2048 + j * 256 + tt0) = p;
    }
  }
}

// ---- k_qm: grid 512. b=x&7, tile=(x>>3)&3 (128c x 128k of M^T), seg=x>>5 (K=128 of jt),
//      A'=Vt3[b] rows c, B'=Qcat2[l] rows k -> Macc[(seg*8+b)][c*256+k] fp32.
__global__ __launch_bounds__(256) void k_qm(const short* __restrict__ Vt3, const short* __restrict__ Qcat2,
                                            float* __restrict__ Macc, int layer) {
  const int x = blockIdx.x, tid = threadIdx.x;
  const int lane = tid & 63, wid = tid >> 6;
  const int b = x & 7, t = (x >> 3) & 3, seg = x >> 5;
  const int r0 = (t >> 1) * 128, c0 = (t & 1) * 128;   // r0: c-dim, c0: k-dim
  const int ar = r0 + (wid >> 1) * 64, bc = c0 + (wid & 1) * 64;
  const short* A = Vt3 + (size_t)b * 524288;
  const short* B = Qcat2 + (size_t)layer * 524288;
  f32x4 acc[4][4];
  #pragma unroll
  for (int f = 0; f < 4; ++f) for (int g = 0; g < 4; ++g) for (int i = 0; i < 4; ++i) acc[f][g][i] = 0.f;
  mm64(A, B, 2048, 2048, ar, bc, seg * 128, seg * 128 + 128, lane, acc);
  float* out = Macc + (size_t)(seg * 8 + b) * 65536;
  #pragma unroll
  for (int f = 0; f < 4; ++f)
    #pragma unroll
    for (int g = 0; g < 4; ++g)
      #pragma unroll
      for (int i = 0; i < 4; ++i)
        out[(size_t)(ar + f * 16 + ((lane >> 4) << 2) + i) * 256 + bc + g * 16 + (lane & 15)] = acc[f][g][i];
}

// ---- k_mred: grid 512. linear 16-seg reduce, *invN -> Mt[b][c][k] bf16.
__global__ __launch_bounds__(256) void k_mred(const float* __restrict__ Macc, short* __restrict__ Mt) {
  const int x = blockIdx.x, tid = threadIdx.x;
  const int i0 = (x * 256 + tid) * 4;
  const int b = i0 >> 16, el = i0 & 65535;
  f32x4 s = {0.f, 0.f, 0.f, 0.f};
  #pragma unroll
  for (int seg = 0; seg < 16; ++seg) {
    f32x4 v = *(const f32x4*)(Macc + (size_t)(seg * 8 + b) * 65536 + el);
    #pragma unroll
    for (int i = 0; i < 4; ++i) s[i] += v[i];
  }
  const float invN = 1.0f / (float)NVAL;
  short4v o;
  #pragma unroll
  for (int i = 0; i < 4; ++i) o[i] = (short)f2b(s[i] * invN);
  *(short4v*)(Mt + (size_t)b * 65536 + el) = o;
}

// ---- k_apply: grid 256. b=x&7, t=x>>3 (0..31): 128n x 128c tile.
//      Z = Zsrc + Zx M (+ label GEMV); fused next-layer staging (Zxbf ping-pong,
//      Zxt via LDS transpose, zlab).
__global__ __launch_bounds__(256) void k_apply(const float* __restrict__ Zsrc, float* __restrict__ Z,
                                               const short* __restrict__ Zxin, const short* __restrict__ Mt,
                                               const float* __restrict__ mcol,
                                               short* __restrict__ Zxout, short* __restrict__ Zxt_out,
                                               float* __restrict__ zlab_out, int wnext) {
  __shared__ short ldsT[128][136];
  const int tid = threadIdx.x, lane = tid & 63, wid = tid >> 6;
  const int wr = wid >> 1, wc = wid & 1;
  const int x = blockIdx.x;
  const int b = x & 7, t = x >> 3;
  const int ar_wg = (t >> 1) * 128, bc_wg = (t & 1) * 128;
  const int ar = ar_wg + wr * 64, bc = bc_wg + wc * 64;
  const short* A = Zxin + (size_t)b * NTOK * DD;
  const short* B = Mt + (size_t)b * 65536;
  const bool gemv = ((t & 1) == 0 && wc == 0);
  f32x4 acc[4][4];
  #pragma unroll
  for (int f = 0; f < 4; ++f) for (int g = 0; g < 4; ++g) for (int i = 0; i < 4; ++i) acc[f][g][i] = 0.f;
  float s[4] = {0.f, 0.f, 0.f, 0.f};
  #pragma unroll 2
  for (int kk = 0; kk < 256; kk += 32) {
    const int kc = kk + ((lane >> 4) << 3);
    short8v av[4], bv[4];
    #pragma unroll
    for (int f = 0; f < 4; ++f)
      av[f] = *(const short8v*)(A + (size_t)(ar + f * 16 + (lane & 15)) * DD + kc);
    #pragma unroll
    for (int g = 0; g < 4; ++g)
      bv[g] = *(const short8v*)(B + (size_t)(bc + g * 16 + (lane & 15)) * 256 + kc);
    if (gemv) {
      const float* mp = mcol + b * 256 + kc;
      f32x4 m0 = *(const f32x4*)mp, m1 = *(const f32x4*)(mp + 4);
      #pragma unroll
      for (int f = 0; f < 4; ++f) {
        #pragma unroll
        for (int q = 0; q < 4; ++q) {
          s[f] += b2f(av[f][q]) * m0[q];
          s[f] += b2f(av[f][4 + q]) * m1[q];
        }
      }
    }
    #pragma unroll
    for (int f = 0; f < 4; ++f)
      #pragma unroll
      for (int g = 0; g < 4; ++g)
        acc[f][g] = __builtin_amdgcn_mfma_f32_16x16x32_bf16(av[f], bv[g], acc[f][g], 0, 0, 0);
  }
  #pragma unroll
  for (int f = 0; f < 4; ++f) {
    const int nb = ar + f * 16 + ((lane >> 4) << 2);
    #pragma unroll
    for (int g = 0; g < 4; ++g) {
      const int c = bc + g * 16 + (lane & 15);
      #pragma unroll
      for (int i = 0; i < 4; ++i) {
        size_t idx = ((size_t)b * NTOK + nb + i) * NCH + c;
        float nv = Zsrc[idx] + acc[f][g][i];
        Z[idx] = nv;
        unsigned short bvv = f2b(nv);
        if (wnext) {
          Zxout[((size_t)b * NTOK + nb + i) * DD + c] = (short)bvv;
          ldsT[c - bc_wg][nb - ar_wg + i] = (nb + i == NVAL) ? (short)0 : (short)bvv;
        }
      }
    }
  }
  if (gemv) {
    #pragma unroll
    for (int f = 0; f < 4; ++f) {
      float tt = s[f];
      tt += __shfl_xor(tt, 16);
      tt += __shfl_xor(tt, 32);
      if ((lane >> 4) == 0) {
        int n = ar + f * 16 + (lane & 15);
        size_t idx = ((size_t)b * NTOK + n) * NCH + DD;
        float nv = Zsrc[idx] + tt;
        Z[idx] = nv;
        if (wnext) zlab_out[b * NTOK + n] = (n == NVAL) ? 0.f : nv;
      }
    }
  }
  if (wnext) {
    __syncthreads();
    const int n0 = (tid & 15) * 8, cr0 = (tid >> 4) * 8;
    #pragma unroll
    for (int r = 0; r < 8; ++r) {
      short8v v = *(const short8v*)&ldsT[cr0 + r][n0];
      *(short8v*)(Zxt_out + ((size_t)b * DD + bc_wg + cr0 + r) * NTOK + ar_wg + n0) = v;
    }
  }
}

// =====================================================================================
extern "C" void kernel_launch(void* const* d_in, const int* in_sizes, int n_in,
                              void* d_out, int out_size, void* d_ws, size_t ws_size,
                              hipStream_t stream) {
  const float* Zin      = (const float*)d_in[0];
  const float* allparam = (const float*)d_in[1];
  float* Z = (float*)d_out;

  // ws layout (bytes)
  const size_t o_zx0  = 0;                         // bf16 [8][2048][256]    8,388,608 (ping)
  const size_t o_zx1  = o_zx0  + 8388608;          // bf16                   8,388,608 (pong)
  const size_t o_zxt  = o_zx1  + 8388608;          // bf16 [8][256][2048]    8,388,608
  const size_t o_acc  = o_zxt  + 8388608;          // f32  [16][8][256][256] 33,554,432 (Gacc/Macc alias)
  const size_t o_gbf  = o_acc  + 33554432;         // bf16 [8][256][256]     1,048,576
  const size_t o_vt   = o_gbf  + 1048576;          // bf16 [8][256][2048]    8,388,608 (Vt3)
  const size_t o_mt   = o_vt   + 8388608;          // bf16 [8][256][256]     1,048,576
  const size_t o_pbf  = o_mt   + 1048576;          // bf16 [4][8][256][256]  4,194,304
  const size_t o_qc2  = o_pbf  + 4194304;          // bf16 [4][256][2048]    4,194,304 (Qcat2)
  const size_t o_qsum = o_qc2  + 4194304;          // f32  [4][256][256]     1,048,576
  const size_t o_gca  = o_qsum + 1048576;          // f32  [8][8][256]       65,536 (gcolacc)
  const size_t o_gcol = o_gca  + 65536;            // f32  [8][256]          8,192
  const size_t o_mcol = o_gcol + 8192;             // f32  [8][256]          8,192
  const size_t o_zlab = o_mcol + 8192;             // f32  [8][2048]         65,536
  const size_t NEED   = o_zlab + 65536;
  if (ws_size < NEED) return;                      // harness ws is larger; never hit

  char* wsb = (char*)d_ws;
  short* Zx[2]   = { (short*)(wsb + o_zx0), (short*)(wsb + o_zx1) };
  short* Zxt     = (short*)(wsb + o_zxt);
  float* Acc     = (float*)(wsb + o_acc);
  short* Gbf     = (short*)(wsb + o_gbf);
  short* Vt3     = (short*)(wsb + o_vt);
  short* Mt      = (short*)(wsb + o_mt);
  short* Pbf     = (short*)(wsb + o_pbf);
  short* Qcat2   = (short*)(wsb + o_qc2);
  float* QsumT   = (float*)(wsb + o_qsum);
  float* gcolacc = (float*)(wsb + o_gca);
  float* gcol    = (float*)(wsb + o_gcol);
  float* mcol    = (float*)(wsb + o_mcol);
  float* zlab    = (float*)(wsb + o_zlab);

  k_init<<<dim3(3136), dim3(256), 0, stream>>>(Zin, allparam, Pbf, Qcat2, QsumT,
                                               Zx[0], Zxt, zlab);

  for (int layer = 0; layer < NL; ++layer) {
    const int cur = layer & 1;
    const int wnext = (layer < NL - 1) ? 1 : 0;
    const float* Zsrc = (layer == 0) ? Zin : Z;
    k_gram<<<dim3(576), dim3(256), 0, stream>>>(Zxt, Zx[cur], zlab, Acc, gcolacc);
    k_gred<<<dim3(520), dim3(256), 0, stream>>>(Acc, gcolacc, Gbf, gcol);
    k_pv<<<dim3(264), dim3(256), 0, stream>>>(Gbf, Pbf, QsumT, gcol, Vt3, mcol, layer);
    k_qm<<<dim3(512), dim3(256), 0, stream>>>(Vt3, Qcat2, Acc, layer);
    k_mred<<<dim3(512), dim3(256), 0, stream>>>(Acc, Mt);
    k_apply<<<dim3(256), dim3(256), 0, stream>>>(Zsrc, Z, Zx[cur], Mt, mcol,
                                                 Zx[cur ^ 1], Zxt, zlab, wnext);
  }
}